// Round 1
// baseline (393.867 us; speedup 1.0000x reference)
//
#include <hip/hip_runtime.h>

#define NN 50000
#define NE 800000
#define DD 128
#define NB 782          // buckets of 64 nodes
#define BSTRIDE 784
#define RPS 50016       // rowptr per-conv stride
#define CHUNK 4096
#define BIN_BLOCKS ((NE + CHUNK - 1) / CHUNK)   // 196
#define H8SCALE 64.f
#define H8INV (1.f / 64.f)

typedef float floatx4 __attribute__((ext_vector_type(4)));
typedef float floatx2 __attribute__((ext_vector_type(2)));
typedef __bf16 bf16x8 __attribute__((ext_vector_type(8)));

__device__ __forceinline__ int clampn(int v) {
    return v < 0 ? 0 : (v >= NN ? NN - 1 : v);
}
__device__ __forceinline__ unsigned int f2bf(float f) {
    union { float f; unsigned int i; } v; v.f = f;
    unsigned int lsb = (v.i >> 16) & 1u;
    v.i += 0x7fffu + lsb;
    return (v.i >> 16) & 0xFFFFu;
}

// ---- W^T bf16 precompute + zero bHist/g (folds the memsets) ----
__global__ __launch_bounds__(256) void k_wt3(const float* __restrict__ w0,
                                             const float* __restrict__ w1,
                                             const float* __restrict__ w2,
                                             unsigned short* __restrict__ wtg,
                                             int* __restrict__ bHist,
                                             float* __restrict__ g) {
    int conv = blockIdx.x;
    const float* W = conv == 0 ? w0 : conv == 1 ? w1 : w2;
    unsigned short* o = wtg + conv * DD * DD;
    for (int i = threadIdx.x; i < BSTRIDE; i += 256) bHist[conv * BSTRIDE + i] = 0;
    for (int i = threadIdx.x; i < DD; i += 256) g[conv * DD + i] = 0.f;
    for (int idx = threadIdx.x; idx < DD * DD; idx += 256) {
        int k = idx >> 7, c = idx & 127;
        o[c * DD + k] = (unsigned short)f2bf(W[idx]);
    }
}

// ---- pass 1: per-bucket edge counts ----
__global__ __launch_bounds__(256) void k_bcnt3(const int* __restrict__ e0,
                                               const int* __restrict__ e1,
                                               const int* __restrict__ e2,
                                               int* __restrict__ bHist) {
    __shared__ int hist[NB];
    const int* ei = (blockIdx.y == 0 ? e0 : blockIdx.y == 1 ? e1 : e2);
    int t = threadIdx.x;
    for (int b = t; b < NB; b += 256) hist[b] = 0;
    __syncthreads();
    int base = blockIdx.x * CHUNK;
    int chunk = NE - base; if (chunk > CHUNK) chunk = CHUNK;
    for (int i = t; i < chunk; i += 256) {
        int d = clampn(ei[NE + base + i]);
        atomicAdd(&hist[d >> 6], 1);
    }
    __syncthreads();
    for (int b = t; b < NB; b += 256)
        if (hist[b]) atomicAdd(&bHist[blockIdx.y * BSTRIDE + b], hist[b]);
}

// ---- pass 2: scan bucket counts -> bOff, bCur ----
__global__ __launch_bounds__(64) void k_bscan3(const int* __restrict__ bHist,
                                               int* __restrict__ bOff,
                                               int* __restrict__ bCur) {
    int conv = blockIdx.x;
    int lane = threadIdx.x;
    const int PER = (NB + 63) / 64;   // 13
    int basei = lane * PER;
    int loc[PER];
    int s = 0;
    for (int j = 0; j < PER; ++j) {
        int b = basei + j;
        int h = (b < NB) ? bHist[conv * BSTRIDE + b] : 0;
        loc[j] = h; s += h;
    }
    int incl = s;
    for (int off = 1; off < 64; off <<= 1) {
        int u = __shfl_up(incl, off);
        if (lane >= off) incl += u;
    }
    int run = incl - s;
    for (int j = 0; j < PER; ++j) {
        int b = basei + j;
        if (b < NB) {
            bOff[conv * BSTRIDE + b] = run;
            bCur[conv * BSTRIDE + b] = run;
            run += loc[j];
        }
    }
    if (lane == 63) bOff[conv * BSTRIDE + NB] = incl;
}

// ---- pass 3: block-local counting sort by bucket, coalesced flush ----
__global__ __launch_bounds__(256) void k_bin3(const int* __restrict__ e0,
                                              const int* __restrict__ e1,
                                              const int* __restrict__ e2,
                                              int* __restrict__ bCur,
                                              unsigned int* __restrict__ binned) {
    __shared__ int hist[NB];
    __shared__ int off[NB];
    __shared__ int delta[NB];
    __shared__ unsigned int stage[CHUNK];
    __shared__ unsigned short sbuck[CHUNK];
    const int* ei = (blockIdx.y == 0 ? e0 : blockIdx.y == 1 ? e1 : e2);
    int conv = blockIdx.y;
    int t = threadIdx.x;
    int base = blockIdx.x * CHUNK;
    int chunk = NE - base; if (chunk > CHUNK) chunk = CHUNK;

    for (int b = t; b < NB; b += 256) hist[b] = 0;
    __syncthreads();
    for (int i = t; i < chunk; i += 256) {
        int d = clampn(ei[NE + base + i]);
        atomicAdd(&hist[d >> 6], 1);
    }
    __syncthreads();
    if (t < 64) {
        const int PER = (NB + 63) / 64;
        int basei = t * PER;
        int loc[(NB + 63) / 64];
        int s = 0;
        for (int j = 0; j < PER; ++j) {
            int b = basei + j;
            int h = (b < NB) ? hist[b] : 0;
            loc[j] = h; s += h;
        }
        int incl = s;
        for (int o = 1; o < 64; o <<= 1) {
            int u = __shfl_up(incl, o);
            if (t >= o) incl += u;
        }
        int run = incl - s;
        for (int j = 0; j < PER; ++j) {
            int b = basei + j;
            if (b < NB) { off[b] = run; run += loc[j]; }
        }
    }
    __syncthreads();
    for (int b = t; b < NB; b += 256) {
        if (hist[b]) {
            int gp = atomicAdd(&bCur[conv * BSTRIDE + b], hist[b]);
            delta[b] = gp - off[b];
        }
    }
    __syncthreads();
    for (int i = t; i < chunk; i += 256) {
        int s = clampn(ei[base + i]);
        int d = clampn(ei[NE + base + i]);
        int b = d >> 6;
        int slot = atomicAdd(&off[b], 1);
        stage[slot] = (unsigned int)s | ((unsigned int)(d & 63) << 16);
        sbuck[slot] = (unsigned short)b;
    }
    __syncthreads();
    for (int i = t; i < chunk; i += 256)
        binned[(long)conv * NE + delta[sbuck[i]] + i] = stage[i];
}

// ---- pass 4: within-bucket sort by node -> adj, deg, rowptr ----
__global__ __launch_bounds__(256) void k_sort3(const unsigned int* __restrict__ binned,
                                               const int* __restrict__ bOff,
                                               int* __restrict__ adj,
                                               int* __restrict__ deg,
                                               int* __restrict__ rowptr) {
    __shared__ int cnt[64];
    __shared__ int cur[64];
    int b = blockIdx.x, conv = blockIdx.y;
    int t = threadIdx.x;
    int beg = bOff[conv * BSTRIDE + b], end = bOff[conv * BSTRIDE + b + 1];
    const unsigned int* bp = binned + (long)conv * NE;
    if (t < 64) cnt[t] = 0;
    __syncthreads();
    for (int i = beg + t; i < end; i += 256)
        atomicAdd(&cnt[(bp[i] >> 16) & 63], 1);
    __syncthreads();
    if (t < 64) {
        int c = cnt[t];
        int incl = c;
        for (int o = 1; o < 64; o <<= 1) {
            int u = __shfl_up(incl, o);
            if (t >= o) incl += u;
        }
        cur[t] = beg + incl - c;
        int v = b * 64 + t;
        if (v < NN) {
            deg[conv * NN + v] = c;
            rowptr[conv * RPS + v] = beg + incl - c;
            if (v == NN - 1) rowptr[conv * RPS + NN] = beg + incl;
        }
    }
    __syncthreads();
    for (int i = beg + t; i < end; i += 256) {
        unsigned int e = bp[i];
        int dl = (e >> 16) & 63;
        int pos = atomicAdd(&cur[dl], 1);
        adj[(long)conv * NE + pos] = (int)(e & 0xFFFFu);
    }
}

// ---- batched MFMA gemm: h' = bf16(x)@bf16(W) * rsqrt(deg+1) * 64 -> fp8 ----
__global__ __launch_bounds__(256) void k_gemmb(
    const float* __restrict__ x0, const float* __restrict__ x1, const float* __restrict__ x2,
    const unsigned short* __restrict__ wtg,
    const int* __restrict__ deg, unsigned char* __restrict__ hp8s, int n) {
    int conv = blockIdx.y;
    const float* x = conv == 0 ? x0 : conv == 1 ? x1 : x2;
    const int* dg = deg + conv * NN;
    unsigned char* hp = hp8s + (size_t)conv * NN * DD;

    __shared__ __align__(16) unsigned short wt[128 * 136];  // W^T bf16, padded
    __shared__ __align__(16) unsigned short xb[64 * 136];   // x rows bf16, padded
    int tid = threadIdx.x;
    int base = blockIdx.x * 64;

    const uint4* wg = reinterpret_cast<const uint4*>(wtg + conv * DD * DD);
#pragma unroll
    for (int it = 0; it < 8; ++it) {
        int chunk = it * 256 + tid;
        int c = chunk >> 4, gq = chunk & 15;
        *reinterpret_cast<uint4*>(&wt[c * 136 + gq * 8]) = wg[chunk];
    }
    const float4* x4p = reinterpret_cast<const float4*>(x);
#pragma unroll
    for (int it = 0; it < 8; ++it) {
        int idx = it * 256 + tid;
        int row = idx >> 5, c4 = idx & 31;
        int r = base + row;
        float4 v = (r < n) ? x4p[(long)r * 32 + c4] : float4{0.f, 0.f, 0.f, 0.f};
        unsigned int p0 = f2bf(v.x) | (f2bf(v.y) << 16);
        unsigned int p1 = f2bf(v.z) | (f2bf(v.w) << 16);
        uint2 pv = {p0, p1};
        *reinterpret_cast<uint2*>(&xb[row * 136 + c4 * 4]) = pv;
    }
    __syncthreads();

    int wave = tid >> 6, lane = tid & 63;
    int quad = lane >> 4, m = lane & 15;
    int rowb = wave * 16;

    bf16x8 a[4];
#pragma unroll
    for (int s = 0; s < 4; ++s)
        a[s] = *reinterpret_cast<const bf16x8*>(&xb[(rowb + m) * 136 + s * 32 + quad * 8]);

    floatx4 acc[8] = {};
#pragma unroll
    for (int j = 0; j < 8; ++j) {
#pragma unroll
        for (int s = 0; s < 4; ++s) {
            bf16x8 b = *reinterpret_cast<const bf16x8*>(&wt[(j * 16 + m) * 136 + s * 32 + quad * 8]);
            acc[j] = __builtin_amdgcn_mfma_f32_16x16x32_bf16(a[s], b, acc[j], 0, 0, 0);
        }
    }
#pragma unroll
    for (int r = 0; r < 4; ++r) {
        int rr = base + rowb + quad * 4 + r;
        if (rr < n) {
            float dv = rsqrtf((float)(dg[rr] + 1)) * H8SCALE;
            unsigned char* rowp = hp + (long)rr * DD;
#pragma unroll
            for (int j = 0; j < 8; ++j) {
                float v = acc[j][r] * dv;
                int p = __builtin_amdgcn_cvt_pk_fp8_f32(v, v, 0, false);
                rowp[j * 16 + m] = (unsigned char)(p & 0xFF);
            }
        }
    }
}

// ---- gather helpers: 16-load burst + consume ----
__device__ __forceinline__ void burst16(const unsigned short* __restrict__ hp,
                                        int lane, int ent, int k, int cnt, int* u) {
#pragma unroll
    for (int q = 0; q < 16; ++q) {
        int idx = k + q; if (idx > cnt - 1) idx = cnt - 1;
        int s = __builtin_amdgcn_readlane(ent, idx);
        unsigned off = ((unsigned)s << 6) | (unsigned)lane;
        u[q] = (int)hp[off];
    }
}
__device__ __forceinline__ void consume16(int k, int cnt, int* u,
                                          float& ax, float& ay, float& cx, float& cy) {
#pragma unroll
    for (int q = 0; q < 16; ++q)
        if (k + q >= cnt) u[q] = 0;
#pragma unroll
    for (int q = 0; q < 16; q += 2) {
        floatx2 f0 = __builtin_amdgcn_cvt_pk_f32_fp8(u[q], false);
        floatx2 f1 = __builtin_amdgcn_cvt_pk_f32_fp8(u[q + 1], false);
        ax += f0.x; ay += f0.y;
        cx += f1.x; cy += f1.y;
    }
}

// ---- batched gather: wave/node, fp8 rows, software-pipelined across nodes ----
// Per node the old version paid a serial chain: rp (s_load) -> ad load -> readlane
// -> 16 gathers -> cvt.  Now: rp[v+stride] issues at the top of node v; the next
// node's ad/self/deg loads issue while node v's 32 gather loads are in flight.
__global__ __launch_bounds__(256) void k_gather3(const unsigned char* __restrict__ hp8s,
                                                 const int* __restrict__ rowptr,
                                                 const int* __restrict__ adj,
                                                 const int* __restrict__ deg,
                                                 const float* __restrict__ cb0,
                                                 const float* __restrict__ cb1,
                                                 const float* __restrict__ cb2,
                                                 float* __restrict__ gout, int n) {
    int conv = blockIdx.y;
    const unsigned short* hp = reinterpret_cast<const unsigned short*>(hp8s + (size_t)conv * NN * DD);
    const int* rp = rowptr + conv * RPS;
    const int* ad = adj + (long)conv * NE;
    const int* dg = deg + conv * NN;
    const float* bias = conv == 0 ? cb0 : conv == 1 ? cb1 : cb2;
    float* go = gout + conv * DD;

    int lane = threadIdx.x & 63;
    int wv = threadIdx.x >> 6;
    int gw = blockIdx.x * 4 + wv;
    int stride = gridDim.x * 4;
    float2 b2 = reinterpret_cast<const float2*>(bias)[lane];
    float px = 0.f, py = 0.f;

    int v = gw;
    if (v < n) {
        // prologue: first node's chain (one-time exposed latency)
        int beg = rp[v], end = rp[v + 1];
        int dgv = dg[v];
        int selfu = (int)hp[((unsigned)v << 6) | (unsigned)lane];
        int ai0 = beg + lane; if (ai0 > NE - 1) ai0 = NE - 1;
        int ent = ad[ai0];

        while (true) {
            int v2 = v + stride;
            int v2c = v2 < n ? v2 : v;
            int beg2 = rp[v2c];            // issue next node's rowptr early (s_load)
            int end2 = rp[v2c + 1];

            int total = end - beg;
            int cnt = total < 64 ? total : 64;

            int u[16], u2[16];
            bool hasA = cnt > 0, hasB = cnt > 16;
            if (hasA) burst16(hp, lane, ent, 0, cnt, u);     // gathers in flight
            if (hasB) burst16(hp, lane, ent, 16, cnt, u2);

            // prefetch next node's adjacency/self/deg while gathers fly
            int aiN = beg2 + lane; if (aiN > NE - 1) aiN = NE - 1;
            int entN = ad[aiN];
            int selfN = (int)hp[((unsigned)v2c << 6) | (unsigned)lane];
            int dgN = dg[v2c];

            floatx2 sf = __builtin_amdgcn_cvt_pk_f32_fp8(selfu, false);
            float ax = sf.x, ay = sf.y, cx = 0.f, cy = 0.f;

            if (hasA) consume16(0, cnt, u, ax, ay, cx, cy);
            if (hasB) consume16(16, cnt, u2, ax, ay, cx, cy);
            if (cnt > 32) {
                burst16(hp, lane, ent, 32, cnt, u);
                if (cnt > 48) burst16(hp, lane, ent, 48, cnt, u2);
                consume16(32, cnt, u, ax, ay, cx, cy);
                if (cnt > 48) consume16(48, cnt, u2, ax, ay, cx, cy);
            }
            // chunks beyond 64 edges (rare: avg deg ~16)
            for (int j = 64; j < total; j += 64) {
                int air = beg + j + lane; if (air > NE - 1) air = NE - 1;
                ent = ad[air];
                int ccnt = total - j; if (ccnt > 64) ccnt = 64;
                burst16(hp, lane, ent, 0, ccnt, u);
                if (ccnt > 16) burst16(hp, lane, ent, 16, ccnt, u2);
                consume16(0, ccnt, u, ax, ay, cx, cy);
                if (ccnt > 16) consume16(16, ccnt, u2, ax, ay, cx, cy);
                if (ccnt > 32) {
                    burst16(hp, lane, ent, 32, ccnt, u);
                    if (ccnt > 48) burst16(hp, lane, ent, 48, ccnt, u2);
                    consume16(32, ccnt, u, ax, ay, cx, cy);
                    if (ccnt > 48) consume16(48, ccnt, u2, ax, ay, cx, cy);
                }
            }

            ax += cx; ay += cy;
            float dv = rsqrtf((float)(dgv + 1)) * H8INV;
            px += fmaxf(dv * ax + b2.x, 0.f);
            py += fmaxf(dv * ay + b2.y, 0.f);

            if (v2 >= n) break;
            v = v2; beg = beg2; end = end2;
            dgv = dgN; selfu = selfN; ent = entN;
        }
    }
    __shared__ float red[4][DD];
    red[wv][lane * 2] = px;
    red[wv][lane * 2 + 1] = py;
    __syncthreads();
    int t = threadIdx.x;
    if (t < DD)
        unsafeAtomicAdd(&go[t], red[0][t] + red[1][t] + red[2][t] + red[3][t]);
}

// ---- head MLP: 256 threads, float4 weight reads, split-j reduction ----
__global__ __launch_bounds__(256) void k_head(const float* __restrict__ g,
    const float* __restrict__ w1, const float* __restrict__ b1,
    const float* __restrict__ w2, const float* __restrict__ b2,
    const float* __restrict__ w3, const float* __restrict__ b3,
    const float* __restrict__ f1w, const float* __restrict__ f1b,
    const float* __restrict__ f2w, const float* __restrict__ f2b,
    float* __restrict__ out) {
    __shared__ float xin[384], part[256], h1[128], h2[128], aw[3], xctx[128];
    int t = threadIdx.x;
    int o = t & 127, half = t >> 7;
    for (int i = t; i < 384; i += 256) xin[i] = g[i];
    __syncthreads();
    // fc1: out o, thread-half splits j in [0,192)/[192,384)
    {
        const float4* wrow = reinterpret_cast<const float4*>(w1 + o * 384 + half * 192);
        const float* xi = xin + half * 192;
        float s = 0.f;
#pragma unroll
        for (int j4 = 0; j4 < 48; ++j4) {
            float4 w = wrow[j4];
            s += w.x * xi[j4 * 4] + w.y * xi[j4 * 4 + 1] + w.z * xi[j4 * 4 + 2] + w.w * xi[j4 * 4 + 3];
        }
        part[t] = s;
    }
    __syncthreads();
    if (t < 128) h1[t] = fmaxf(part[t] + part[t + 128] + b1[t], 0.f);
    __syncthreads();
    // fc2
    {
        const float4* wrow = reinterpret_cast<const float4*>(w2 + o * 128 + half * 64);
        const float* xi = h1 + half * 64;
        float s = 0.f;
#pragma unroll
        for (int j4 = 0; j4 < 16; ++j4) {
            float4 w = wrow[j4];
            s += w.x * xi[j4 * 4] + w.y * xi[j4 * 4 + 1] + w.z * xi[j4 * 4 + 2] + w.w * xi[j4 * 4 + 3];
        }
        part[t] = s;
    }
    __syncthreads();
    if (t < 128) h2[t] = fmaxf(part[t] + part[t + 128] + b2[t], 0.f);
    __syncthreads();
    if (t < 3) {
        float sl = b3[t];
        for (int j = 0; j < 128; ++j) sl += h2[j] * w3[t * 128 + j];
        aw[t] = sl;
    }
    __syncthreads();
    if (t == 0) {
        float mx = fmaxf(aw[0], fmaxf(aw[1], aw[2]));
        float e0 = expf(aw[0] - mx), e1 = expf(aw[1] - mx), e2 = expf(aw[2] - mx);
        float inv = 1.f / (e0 + e1 + e2);
        aw[0] = e0 * inv; aw[1] = e1 * inv; aw[2] = e2 * inv;
    }
    __syncthreads();
    if (t < 128) xctx[t] = aw[0] * xin[t] + aw[1] * xin[128 + t] + aw[2] * xin[256 + t];
    __syncthreads();
    // FiLM: half 0 -> gamma (f1), half 1 -> beta (f2), in parallel
    {
        const float* fw = half ? f2w : f1w;
        const float* fb = half ? f2b : f1b;
        const float4* wrow = reinterpret_cast<const float4*>(fw + o * 128);
        float s = fb[o];
#pragma unroll
        for (int j4 = 0; j4 < 32; ++j4) {
            float4 w = wrow[j4];
            s += w.x * xctx[j4 * 4] + w.y * xctx[j4 * 4 + 1] + w.z * xctx[j4 * 4 + 2] + w.w * xctx[j4 * 4 + 3];
        }
        out[half * 128 + o] = tanhf(s);
    }
}

extern "C" void kernel_launch(void* const* d_in, const int* in_sizes, int n_in,
                              void* d_out, int out_size, void* d_ws, size_t ws_size,
                              hipStream_t stream) {
    (void)in_sizes; (void)n_in; (void)out_size; (void)ws_size;

    const float* x[3]  = {(const float*)d_in[0], (const float*)d_in[1], (const float*)d_in[2]};
    const int*   ei[3] = {(const int*)d_in[3], (const int*)d_in[4], (const int*)d_in[5]};
    const float* cw[3] = {(const float*)d_in[6], (const float*)d_in[8], (const float*)d_in[10]};
    const float* cb[3] = {(const float*)d_in[7], (const float*)d_in[9], (const float*)d_in[11]};

    // layout (binned overlaid by hp8: binned dead after k_sort3)
    char* ws = (char*)d_ws;
    int*            adj    = (int*)ws;                         //  9,600,000
    int*            deg    = (int*)(ws + 9600000);             //    600,000
    int*            rowptr = (int*)(ws + 10200000);            //    600,192
    int*            bHist  = (int*)(ws + 10800192);            //      9,408
    int*            bOff   = (int*)(ws + 10809600);            //      9,408
    int*            bCur   = (int*)(ws + 10819008);            //      9,408
    float*          g      = (float*)(ws + 10828416);          //      1,536
    unsigned short* wtg    = (unsigned short*)(ws + 10830080); //     98,304
    char*           uni    = ws + 10928384;                    // union region
    unsigned int*   binned = (unsigned int*)uni;               //  9,600,000
    unsigned char*  hp8    = (unsigned char*)uni;              // 19,200,000

    dim3 bin_grid(BIN_BLOCKS, 3);
    k_wt3   <<<3, 256, 0, stream>>>(cw[0], cw[1], cw[2], wtg, bHist, g);
    k_bcnt3 <<<bin_grid, 256, 0, stream>>>(ei[0], ei[1], ei[2], bHist);
    k_bscan3<<<3, 64, 0, stream>>>(bHist, bOff, bCur);
    k_bin3  <<<bin_grid, 256, 0, stream>>>(ei[0], ei[1], ei[2], bCur, binned);
    k_sort3 <<<dim3(NB, 3), 256, 0, stream>>>(binned, bOff, adj, deg, rowptr);

    k_gemmb<<<dim3(NB, 3), 256, 0, stream>>>(x[0], x[1], x[2], wtg, deg, hp8, NN);
    k_gather3<<<dim3(2048, 3), 256, 0, stream>>>(hp8, rowptr, adj, deg,
                                                 cb[0], cb[1], cb[2], g, NN);

    k_head<<<1, 256, 0, stream>>>(g,
        (const float*)d_in[12], (const float*)d_in[13],
        (const float*)d_in[14], (const float*)d_in[15],
        (const float*)d_in[16], (const float*)d_in[17],
        (const float*)d_in[18], (const float*)d_in[19],
        (const float*)d_in[20], (const float*)d_in[21],
        (float*)d_out);
}

// Round 2
// 379.382 us; speedup vs baseline: 1.0382x; 1.0382x over previous
//
#include <hip/hip_runtime.h>

#define NN 50000
#define NE 800000
#define DD 128
#define NB 782          // buckets of 64 nodes
#define BSTRIDE 784
#define RPS 50016       // rowptr per-conv stride
#define CHUNK 4096
#define BIN_BLOCKS ((NE + CHUNK - 1) / CHUNK)   // 196
#define H8SCALE 64.f
#define H8INV (1.f / 64.f)
#define HROWS (NN + 1)  // hp8 rows per conv; row NN is the all-zero row

typedef float floatx4 __attribute__((ext_vector_type(4)));
typedef float floatx2 __attribute__((ext_vector_type(2)));
typedef __bf16 bf16x8 __attribute__((ext_vector_type(8)));

__device__ __forceinline__ int clampn(int v) {
    return v < 0 ? 0 : (v >= NN ? NN - 1 : v);
}
__device__ __forceinline__ unsigned int f2bf(float f) {
    union { float f; unsigned int i; } v; v.f = f;
    unsigned int lsb = (v.i >> 16) & 1u;
    v.i += 0x7fffu + lsb;
    return (v.i >> 16) & 0xFFFFu;
}

// ---- W^T bf16 precompute + zero bHist/g (folds the memsets) ----
__global__ __launch_bounds__(256) void k_wt3(const float* __restrict__ w0,
                                             const float* __restrict__ w1,
                                             const float* __restrict__ w2,
                                             unsigned short* __restrict__ wtg,
                                             int* __restrict__ bHist,
                                             float* __restrict__ g) {
    int conv = blockIdx.x;
    const float* W = conv == 0 ? w0 : conv == 1 ? w1 : w2;
    unsigned short* o = wtg + conv * DD * DD;
    for (int i = threadIdx.x; i < BSTRIDE; i += 256) bHist[conv * BSTRIDE + i] = 0;
    for (int i = threadIdx.x; i < DD; i += 256) g[conv * DD + i] = 0.f;
    for (int idx = threadIdx.x; idx < DD * DD; idx += 256) {
        int k = idx >> 7, c = idx & 127;
        o[c * DD + k] = (unsigned short)f2bf(W[idx]);
    }
}

// ---- pass 1: per-bucket edge counts ----
__global__ __launch_bounds__(256) void k_bcnt3(const int* __restrict__ e0,
                                               const int* __restrict__ e1,
                                               const int* __restrict__ e2,
                                               int* __restrict__ bHist) {
    __shared__ int hist[NB];
    const int* ei = (blockIdx.y == 0 ? e0 : blockIdx.y == 1 ? e1 : e2);
    int t = threadIdx.x;
    for (int b = t; b < NB; b += 256) hist[b] = 0;
    __syncthreads();
    int base = blockIdx.x * CHUNK;
    int chunk = NE - base; if (chunk > CHUNK) chunk = CHUNK;
    for (int i = t; i < chunk; i += 256) {
        int d = clampn(ei[NE + base + i]);
        atomicAdd(&hist[d >> 6], 1);
    }
    __syncthreads();
    for (int b = t; b < NB; b += 256)
        if (hist[b]) atomicAdd(&bHist[blockIdx.y * BSTRIDE + b], hist[b]);
}

// ---- pass 2: scan bucket counts -> bOff, bCur ----
__global__ __launch_bounds__(64) void k_bscan3(const int* __restrict__ bHist,
                                               int* __restrict__ bOff,
                                               int* __restrict__ bCur) {
    int conv = blockIdx.x;
    int lane = threadIdx.x;
    const int PER = (NB + 63) / 64;   // 13
    int basei = lane * PER;
    int loc[PER];
    int s = 0;
    for (int j = 0; j < PER; ++j) {
        int b = basei + j;
        int h = (b < NB) ? bHist[conv * BSTRIDE + b] : 0;
        loc[j] = h; s += h;
    }
    int incl = s;
    for (int off = 1; off < 64; off <<= 1) {
        int u = __shfl_up(incl, off);
        if (lane >= off) incl += u;
    }
    int run = incl - s;
    for (int j = 0; j < PER; ++j) {
        int b = basei + j;
        if (b < NB) {
            bOff[conv * BSTRIDE + b] = run;
            bCur[conv * BSTRIDE + b] = run;
            run += loc[j];
        }
    }
    if (lane == 63) bOff[conv * BSTRIDE + NB] = incl;
}

// ---- pass 3: block-local counting sort by bucket, coalesced flush ----
__global__ __launch_bounds__(256) void k_bin3(const int* __restrict__ e0,
                                              const int* __restrict__ e1,
                                              const int* __restrict__ e2,
                                              int* __restrict__ bCur,
                                              unsigned int* __restrict__ binned) {
    __shared__ int hist[NB];
    __shared__ int off[NB];
    __shared__ int delta[NB];
    __shared__ unsigned int stage[CHUNK];
    __shared__ unsigned short sbuck[CHUNK];
    const int* ei = (blockIdx.y == 0 ? e0 : blockIdx.y == 1 ? e1 : e2);
    int conv = blockIdx.y;
    int t = threadIdx.x;
    int base = blockIdx.x * CHUNK;
    int chunk = NE - base; if (chunk > CHUNK) chunk = CHUNK;

    for (int b = t; b < NB; b += 256) hist[b] = 0;
    __syncthreads();
    for (int i = t; i < chunk; i += 256) {
        int d = clampn(ei[NE + base + i]);
        atomicAdd(&hist[d >> 6], 1);
    }
    __syncthreads();
    if (t < 64) {
        const int PER = (NB + 63) / 64;
        int basei = t * PER;
        int loc[(NB + 63) / 64];
        int s = 0;
        for (int j = 0; j < PER; ++j) {
            int b = basei + j;
            int h = (b < NB) ? hist[b] : 0;
            loc[j] = h; s += h;
        }
        int incl = s;
        for (int o = 1; o < 64; o <<= 1) {
            int u = __shfl_up(incl, o);
            if (t >= o) incl += u;
        }
        int run = incl - s;
        for (int j = 0; j < PER; ++j) {
            int b = basei + j;
            if (b < NB) { off[b] = run; run += loc[j]; }
        }
    }
    __syncthreads();
    for (int b = t; b < NB; b += 256) {
        if (hist[b]) {
            int gp = atomicAdd(&bCur[conv * BSTRIDE + b], hist[b]);
            delta[b] = gp - off[b];
        }
    }
    __syncthreads();
    for (int i = t; i < chunk; i += 256) {
        int s = clampn(ei[base + i]);
        int d = clampn(ei[NE + base + i]);
        int b = d >> 6;
        int slot = atomicAdd(&off[b], 1);
        stage[slot] = (unsigned int)s | ((unsigned int)(d & 63) << 16);
        sbuck[slot] = (unsigned short)b;
    }
    __syncthreads();
    for (int i = t; i < chunk; i += 256)
        binned[(long)conv * NE + delta[sbuck[i]] + i] = stage[i];
}

// ---- pass 4: within-bucket sort by node -> adj, deg, rowptr ----
__global__ __launch_bounds__(256) void k_sort3(const unsigned int* __restrict__ binned,
                                               const int* __restrict__ bOff,
                                               int* __restrict__ adj,
                                               int* __restrict__ deg,
                                               int* __restrict__ rowptr) {
    __shared__ int cnt[64];
    __shared__ int cur[64];
    int b = blockIdx.x, conv = blockIdx.y;
    int t = threadIdx.x;
    int beg = bOff[conv * BSTRIDE + b], end = bOff[conv * BSTRIDE + b + 1];
    const unsigned int* bp = binned + (long)conv * NE;
    if (t < 64) cnt[t] = 0;
    __syncthreads();
    for (int i = beg + t; i < end; i += 256)
        atomicAdd(&cnt[(bp[i] >> 16) & 63], 1);
    __syncthreads();
    if (t < 64) {
        int c = cnt[t];
        int incl = c;
        for (int o = 1; o < 64; o <<= 1) {
            int u = __shfl_up(incl, o);
            if (t >= o) incl += u;
        }
        cur[t] = beg + incl - c;
        int v = b * 64 + t;
        if (v < NN) {
            deg[conv * NN + v] = c;
            rowptr[conv * RPS + v] = beg + incl - c;
            if (v == NN - 1) rowptr[conv * RPS + NN] = beg + incl;
        }
    }
    __syncthreads();
    for (int i = beg + t; i < end; i += 256) {
        unsigned int e = bp[i];
        int dl = (e >> 16) & 63;
        int pos = atomicAdd(&cur[dl], 1);
        adj[(long)conv * NE + pos] = (int)(e & 0xFFFFu);
    }
}

// ---- batched MFMA gemm: h' = bf16(x)@bf16(W) * rsqrt(deg+1) * 64 -> fp8 ----
// also zeros row NN (the padding target row for k_gather3)
__global__ __launch_bounds__(256) void k_gemmb(
    const float* __restrict__ x0, const float* __restrict__ x1, const float* __restrict__ x2,
    const unsigned short* __restrict__ wtg,
    const int* __restrict__ deg, unsigned char* __restrict__ hp8s, int n) {
    int conv = blockIdx.y;
    const float* x = conv == 0 ? x0 : conv == 1 ? x1 : x2;
    const int* dg = deg + conv * NN;
    unsigned char* hp = hp8s + (size_t)conv * HROWS * DD;

    __shared__ __align__(16) unsigned short wt[128 * 136];  // W^T bf16, padded
    __shared__ __align__(16) unsigned short xb[64 * 136];   // x rows bf16, padded
    int tid = threadIdx.x;
    int base = blockIdx.x * 64;

    if (blockIdx.x == 0 && tid < 32)
        reinterpret_cast<unsigned int*>(hp + (size_t)NN * DD)[tid] = 0u;

    const uint4* wg = reinterpret_cast<const uint4*>(wtg + conv * DD * DD);
#pragma unroll
    for (int it = 0; it < 8; ++it) {
        int chunk = it * 256 + tid;
        int c = chunk >> 4, gq = chunk & 15;
        *reinterpret_cast<uint4*>(&wt[c * 136 + gq * 8]) = wg[chunk];
    }
    const float4* x4p = reinterpret_cast<const float4*>(x);
#pragma unroll
    for (int it = 0; it < 8; ++it) {
        int idx = it * 256 + tid;
        int row = idx >> 5, c4 = idx & 31;
        int r = base + row;
        float4 v = (r < n) ? x4p[(long)r * 32 + c4] : float4{0.f, 0.f, 0.f, 0.f};
        unsigned int p0 = f2bf(v.x) | (f2bf(v.y) << 16);
        unsigned int p1 = f2bf(v.z) | (f2bf(v.w) << 16);
        uint2 pv = {p0, p1};
        *reinterpret_cast<uint2*>(&xb[row * 136 + c4 * 4]) = pv;
    }
    __syncthreads();

    int wave = tid >> 6, lane = tid & 63;
    int quad = lane >> 4, m = lane & 15;
    int rowb = wave * 16;

    bf16x8 a[4];
#pragma unroll
    for (int s = 0; s < 4; ++s)
        a[s] = *reinterpret_cast<const bf16x8*>(&xb[(rowb + m) * 136 + s * 32 + quad * 8]);

    floatx4 acc[8] = {};
#pragma unroll
    for (int j = 0; j < 8; ++j) {
#pragma unroll
        for (int s = 0; s < 4; ++s) {
            bf16x8 b = *reinterpret_cast<const bf16x8*>(&wt[(j * 16 + m) * 136 + s * 32 + quad * 8]);
            acc[j] = __builtin_amdgcn_mfma_f32_16x16x32_bf16(a[s], b, acc[j], 0, 0, 0);
        }
    }
#pragma unroll
    for (int r = 0; r < 4; ++r) {
        int rr = base + rowb + quad * 4 + r;
        if (rr < n) {
            float dv = rsqrtf((float)(dg[rr] + 1)) * H8SCALE;
            unsigned char* rowp = hp + (long)rr * DD;
#pragma unroll
            for (int j = 0; j < 8; ++j) {
                float v = acc[j][r] * dv;
                int p = __builtin_amdgcn_cvt_pk_fp8_f32(v, v, 0, false);
                rowp[j * 16 + m] = (unsigned char)(p & 0xFF);
            }
        }
    }
}

// ---- batched gather: wave processes a NODE PAIR (lane-half 0 -> v=2p, half 1 -> 2p+1).
// dword loads: 4 fp8 channels/lane, 32 lanes cover a 128B row => 2 edge-rows per load instr.
// Edge indices broadcast per-half via ds_bpermute; phantom slots read the zero row (NN)
// via ent-padding, so no per-load clamps or masks. ----
#define GBURST(UA, BOFS)                                                              \
    _Pragma("unroll")                                                                 \
    for (int q = 0; q < 8; ++q) {                                                     \
        int s = __builtin_amdgcn_ds_bpermute(bpbase + (BOFS) + 4 * q, ent);           \
        UA[q] = *reinterpret_cast<const unsigned int*>(hpb + (((unsigned)s << 7) | loff)); \
    }
#define GCONSUME(UA)                                                                  \
    _Pragma("unroll")                                                                 \
    for (int q = 0; q < 8; ++q) {                                                     \
        floatx2 f0 = __builtin_amdgcn_cvt_pk_f32_fp8((int)UA[q], false);              \
        floatx2 f1 = __builtin_amdgcn_cvt_pk_f32_fp8((int)UA[q], true);               \
        e0 += f0.x; e1 += f0.y; e2 += f1.x; e3 += f1.y;                               \
    }

__global__ __launch_bounds__(256) void k_gather3(const unsigned char* __restrict__ hp8s,
                                                 const int* __restrict__ rowptr,
                                                 const int* __restrict__ adj,
                                                 const float* __restrict__ cb0,
                                                 const float* __restrict__ cb1,
                                                 const float* __restrict__ cb2,
                                                 float* __restrict__ gout) {
    int conv = blockIdx.y;
    const unsigned char* hpb = hp8s + (size_t)conv * HROWS * DD;
    const int* rp = rowptr + conv * RPS;
    const int* ad = adj + (long)conv * NE;
    const float* bias = conv == 0 ? cb0 : conv == 1 ? cb1 : cb2;
    float* go = gout + conv * DD;

    int lane = threadIdx.x & 63;
    int wv = threadIdx.x >> 6;
    int l5 = lane & 31;
    int half = lane >> 5;
    int bpbase = half << 7;           // bpermute byte base: own half's 32 ent lanes
    unsigned loff = (unsigned)(l5 << 2); // channel byte offset within a 128B row
    float4 b4 = reinterpret_cast<const float4*>(bias)[l5];
    float p0 = 0.f, p1 = 0.f, p2 = 0.f, p3 = 0.f;

    int gw = blockIdx.x * 4 + wv;
    int stride = gridDim.x * 4;
    const int NPAIR = NN / 2;

    for (int p = gw; p < NPAIR; p += stride) {
        int v = p * 2 + half;                   // per-lane node
        int beg = rp[v];
        int end = rp[v + 1];
        int cnt = end - beg;                    // in-degree (self separate)
        int cother = __shfl_xor(cnt, 32);
        int cmax = cnt > cother ? cnt : cother; // uniform across wave

        float e0 = 0.f, e1 = 0.f, e2 = 0.f, e3 = 0.f;
        for (int wk = 0; wk < cmax; wk += 32) {
            int widx = wk + l5;
            int ai = beg + widx; ai = ai < NE ? ai : NE - 1;
            int ent = ad[ai];
            ent = (widx < cnt) ? ent : NN;      // pad -> zero row
            int r = cmax - wk;
            unsigned int u0[8], u1[8];
            GBURST(u0, 0)
            if (r > 8)  { GBURST(u1, 32) }
            GCONSUME(u0)
            if (r > 8)  { GCONSUME(u1) }
            if (r > 16) {
                GBURST(u0, 64)
                if (r > 24) { GBURST(u1, 96) }
                GCONSUME(u0)
                if (r > 24) { GCONSUME(u1) }
            }
        }
        // self + norm + bias + relu, per-lane (each half owns its node)
        unsigned int us = *reinterpret_cast<const unsigned int*>(hpb + (((unsigned)v << 7) | loff));
        floatx2 s0 = __builtin_amdgcn_cvt_pk_f32_fp8((int)us, false);
        floatx2 s1 = __builtin_amdgcn_cvt_pk_f32_fp8((int)us, true);
        float dv = rsqrtf((float)(cnt + 1)) * H8INV;
        p0 += fmaxf(dv * (e0 + s0.x) + b4.x, 0.f);
        p1 += fmaxf(dv * (e1 + s0.y) + b4.y, 0.f);
        p2 += fmaxf(dv * (e2 + s1.x) + b4.z, 0.f);
        p3 += fmaxf(dv * (e3 + s1.y) + b4.w, 0.f);
    }

    // fold the two halves (different node subsets, same channels)
    p0 += __shfl_xor(p0, 32);
    p1 += __shfl_xor(p1, 32);
    p2 += __shfl_xor(p2, 32);
    p3 += __shfl_xor(p3, 32);

    __shared__ float red[4][DD];
    if (half == 0) {
        float4 pv = {p0, p1, p2, p3};
        *reinterpret_cast<float4*>(&red[wv][l5 * 4]) = pv;
    }
    __syncthreads();
    int t = threadIdx.x;
    if (t < DD)
        unsafeAtomicAdd(&go[t], red[0][t] + red[1][t] + red[2][t] + red[3][t]);
}

// ---- head MLP: 256 threads, float4 weight reads, split-j reduction ----
__global__ __launch_bounds__(256) void k_head(const float* __restrict__ g,
    const float* __restrict__ w1, const float* __restrict__ b1,
    const float* __restrict__ w2, const float* __restrict__ b2,
    const float* __restrict__ w3, const float* __restrict__ b3,
    const float* __restrict__ f1w, const float* __restrict__ f1b,
    const float* __restrict__ f2w, const float* __restrict__ f2b,
    float* __restrict__ out) {
    __shared__ float xin[384], part[256], h1[128], h2[128], aw[3], xctx[128];
    int t = threadIdx.x;
    int o = t & 127, half = t >> 7;
    for (int i = t; i < 384; i += 256) xin[i] = g[i];
    __syncthreads();
    // fc1: out o, thread-half splits j in [0,192)/[192,384)
    {
        const float4* wrow = reinterpret_cast<const float4*>(w1 + o * 384 + half * 192);
        const float* xi = xin + half * 192;
        float s = 0.f;
#pragma unroll
        for (int j4 = 0; j4 < 48; ++j4) {
            float4 w = wrow[j4];
            s += w.x * xi[j4 * 4] + w.y * xi[j4 * 4 + 1] + w.z * xi[j4 * 4 + 2] + w.w * xi[j4 * 4 + 3];
        }
        part[t] = s;
    }
    __syncthreads();
    if (t < 128) h1[t] = fmaxf(part[t] + part[t + 128] + b1[t], 0.f);
    __syncthreads();
    // fc2
    {
        const float4* wrow = reinterpret_cast<const float4*>(w2 + o * 128 + half * 64);
        const float* xi = h1 + half * 64;
        float s = 0.f;
#pragma unroll
        for (int j4 = 0; j4 < 16; ++j4) {
            float4 w = wrow[j4];
            s += w.x * xi[j4 * 4] + w.y * xi[j4 * 4 + 1] + w.z * xi[j4 * 4 + 2] + w.w * xi[j4 * 4 + 3];
        }
        part[t] = s;
    }
    __syncthreads();
    if (t < 128) h2[t] = fmaxf(part[t] + part[t + 128] + b2[t], 0.f);
    __syncthreads();
    if (t < 3) {
        float sl = b3[t];
        for (int j = 0; j < 128; ++j) sl += h2[j] * w3[t * 128 + j];
        aw[t] = sl;
    }
    __syncthreads();
    if (t == 0) {
        float mx = fmaxf(aw[0], fmaxf(aw[1], aw[2]));
        float e0 = expf(aw[0] - mx), e1 = expf(aw[1] - mx), e2 = expf(aw[2] - mx);
        float inv = 1.f / (e0 + e1 + e2);
        aw[0] = e0 * inv; aw[1] = e1 * inv; aw[2] = e2 * inv;
    }
    __syncthreads();
    if (t < 128) xctx[t] = aw[0] * xin[t] + aw[1] * xin[128 + t] + aw[2] * xin[256 + t];
    __syncthreads();
    // FiLM: half 0 -> gamma (f1), half 1 -> beta (f2), in parallel
    {
        const float* fw = half ? f2w : f1w;
        const float* fb = half ? f2b : f1b;
        const float4* wrow = reinterpret_cast<const float4*>(fw + o * 128);
        float s = fb[o];
#pragma unroll
        for (int j4 = 0; j4 < 32; ++j4) {
            float4 w = wrow[j4];
            s += w.x * xctx[j4 * 4] + w.y * xctx[j4 * 4 + 1] + w.z * xctx[j4 * 4 + 2] + w.w * xctx[j4 * 4 + 3];
        }
        out[half * 128 + o] = tanhf(s);
    }
}

extern "C" void kernel_launch(void* const* d_in, const int* in_sizes, int n_in,
                              void* d_out, int out_size, void* d_ws, size_t ws_size,
                              hipStream_t stream) {
    (void)in_sizes; (void)n_in; (void)out_size; (void)ws_size;

    const float* x[3]  = {(const float*)d_in[0], (const float*)d_in[1], (const float*)d_in[2]};
    const int*   ei[3] = {(const int*)d_in[3], (const int*)d_in[4], (const int*)d_in[5]};
    const float* cw[3] = {(const float*)d_in[6], (const float*)d_in[8], (const float*)d_in[10]};
    const float* cb[3] = {(const float*)d_in[7], (const float*)d_in[9], (const float*)d_in[11]};

    // layout (binned overlaid by hp8: binned dead after k_sort3)
    char* ws = (char*)d_ws;
    int*            adj    = (int*)ws;                         //  9,600,000
    int*            deg    = (int*)(ws + 9600000);             //    600,000
    int*            rowptr = (int*)(ws + 10200000);            //    600,192
    int*            bHist  = (int*)(ws + 10800192);            //      9,408
    int*            bOff   = (int*)(ws + 10809600);            //      9,408
    int*            bCur   = (int*)(ws + 10819008);            //      9,408
    float*          g      = (float*)(ws + 10828416);          //      1,536
    unsigned short* wtg    = (unsigned short*)(ws + 10830080); //     98,304
    char*           uni    = ws + 10928384;                    // union region
    unsigned int*   binned = (unsigned int*)uni;               //  9,600,000
    unsigned char*  hp8    = (unsigned char*)uni;              // 19,200,384 (3 x (NN+1) x 128)

    dim3 bin_grid(BIN_BLOCKS, 3);
    k_wt3   <<<3, 256, 0, stream>>>(cw[0], cw[1], cw[2], wtg, bHist, g);
    k_bcnt3 <<<bin_grid, 256, 0, stream>>>(ei[0], ei[1], ei[2], bHist);
    k_bscan3<<<3, 64, 0, stream>>>(bHist, bOff, bCur);
    k_bin3  <<<bin_grid, 256, 0, stream>>>(ei[0], ei[1], ei[2], bCur, binned);
    k_sort3 <<<dim3(NB, 3), 256, 0, stream>>>(binned, bOff, adj, deg, rowptr);

    k_gemmb<<<dim3(NB, 3), 256, 0, stream>>>(x[0], x[1], x[2], wtg, deg, hp8, NN);
    k_gather3<<<dim3(2048, 3), 256, 0, stream>>>(hp8, rowptr, adj,
                                                 cb[0], cb[1], cb[2], g);

    k_head<<<1, 256, 0, stream>>>(g,
        (const float*)d_in[12], (const float*)d_in[13],
        (const float*)d_in[14], (const float*)d_in[15],
        (const float*)d_in[16], (const float*)d_in[17],
        (const float*)d_in[18], (const float*)d_in[19],
        (const float*)d_in[20], (const float*)d_in[21],
        (float*)d_out);
}